// Round 8
// baseline (373.418 us; speedup 1.0000x reference)
//
#include <hip/hip_runtime.h>
#include <hip/hip_bf16.h>
#include <hip/hip_cooperative_groups.h>

// SpectralConv2d: B=8, CIN=COUT=32, N=4096, modes 32x x 31y (u_ft needs y 0..15)
// r8: single cooperative kernel (256 blocks x 512 thr, 1/CU), grid.sync between
// phases; math identical to r7 (passing, absmax 0.00195). Fallback: 4 plain
// kernels with the same device-function bodies if cooperative launch fails.
//
// ws (u32 slots), 18.9 MB:
//   E2in  [8][16][4096]           : 524288   (aliased by A32 in phase2/3)
//   B_pre [8][64ch][64j][64n]     : 2097152
//   P     [8s][8b][16y][32c][64j] : 2097152 f32

#define NPTS 4096
#define TDIM 128
#define TWO_PI 6.283185307179586f

namespace cg = cooperative_groups;

typedef __attribute__((ext_vector_type(8))) short bf16x8;
typedef __attribute__((ext_vector_type(4))) float f32x4;
typedef unsigned int u32;
typedef unsigned short u16;

__device__ __forceinline__ u32 pack2(float a, float b) {
  __hip_bfloat162 h = __float22bfloat162_rn(make_float2(a, b));  // v_cvt_pk_bf16_f32
  u32 r; __builtin_memcpy(&r, &h, 4); return r;
}
__device__ __forceinline__ float bflo(u32 u) { return __uint_as_float(u << 16); }
__device__ __forceinline__ float bfhi(u32 u) { return __uint_as_float(u & 0xFFFF0000u); }
__device__ __forceinline__ bf16x8 as_frag(uint4 v) {
  bf16x8 f; __builtin_memcpy(&f, &v, 16); return f;
}

// ---------------------------------------------------------------------------
// Phase 0 == r7 prep1 (512x256 remapped to 256x512): E2in + B_pre tables.
__device__ __forceinline__ void phase0(int bid, int tid,
    const float* __restrict__ x_in, u32* __restrict__ E2in, u32* __restrict__ B_pre) {
  const int obid = (bid << 1) | (tid >> 8);   // 0..511
  const int ot = tid & 255;
  const int b = obid & 7, ntile = obid >> 3;  // 0..63
  const int nl = ot & 63, task = ot >> 6;
  const int n = ntile * 64 + nl;
  float2 xv = *(const float2*)&x_in[(size_t)(b * NPTS + n) * 2];
  if (task < 2) {
    #pragma unroll
    for (int k = 0; k < 8; ++k) {
      int y = task * 8 + k;                          // 0..15 -> k2y = y
      float th = TWO_PI * xv.y * (float)y;
      float s, c; __sincosf(th, &s, &c);
      E2in[((b * 16 + y) << 12) + n] = pack2(c, s);
    }
  } else {
    u32* base = B_pre + (size_t)(b * 64 + ntile) * 4096;
    #pragma unroll
    for (int k = 0; k < 16; ++k) {
      int x = (task - 2) * 16 + k;
      float k1x = (x < 16) ? (float)x : (float)(x - 32);
      float th = TWO_PI * xv.x * k1x;
      float s, c; __sincosf(th, &s, &c);
      base[(2 * x) * 64 + nl]     = pack2(c, s);     // conj(e1) re-row
      base[(2 * x + 1) * 64 + nl] = pack2(-s, c);    // conj(e1) im-row
    }
  }
}

// ---------------------------------------------------------------------------
// Phase 1 == r7 uft (512 4-wave units on 256 8-wave blocks). No LDS/barriers.
__device__ __forceinline__ void phase1(int bid, int tid,
    const float* __restrict__ u, const u32* __restrict__ E2in,
    const u32* __restrict__ B_pre, float* __restrict__ P) {
  const int b = bid & 7;                       // XCD pin
  const int unit = ((bid >> 3) << 1) | (tid >> 8);   // 0..63
  const int yp = unit & 7;
  const int s = unit >> 3;
  const int lt = tid & 255;
  const int lane = lt & 63, wu = lt >> 6;

  const int y0 = 2 * yp, y1 = 2 * yp + 1;
  const int colw = lane & 15, kq = lane >> 4;
  const int brow = wu * 16 + colw;

  const float* u0p = &u[(size_t)(b * 32 + colw) * NPTS];
  const float* u1p = &u[(size_t)(b * 32 + colw + 16) * NPTS];
  const u32* e0p = &E2in[(b * 16 + y0) << 12];
  const u32* e1p = &E2in[(b * 16 + y1) << 12];
  const u32* bp  = B_pre + (size_t)(b * 64 + s * 8) * 4096 + brow * 64 + kq * 4;

  f32x4 acc00 = {0,0,0,0}, acc01 = {0,0,0,0}, acc10 = {0,0,0,0}, acc11 = {0,0,0,0};

  #pragma unroll 1
  for (int ch = 0; ch < 8; ++ch) {
    const int nq0 = s * 512 + ch * 64 + kq * 4;
    #pragma unroll
    for (int ks = 0; ks < 4; ++ks) {
      const int nq = nq0 + ks * 16;
      float4 uv0 = *(const float4*)(u0p + nq);
      float4 uv1 = *(const float4*)(u1p + nq);
      uint4 e0 = *(const uint4*)(e0p + nq);
      uint4 e1 = *(const uint4*)(e1p + nq);
      uint4 bb = *(const uint4*)(bp + (size_t)ch * 4096 + ks * 16);

      const float uu0[4] = {uv0.x, uv0.y, uv0.z, uv0.w};
      const float uu1[4] = {uv1.x, uv1.y, uv1.z, uv1.w};
      const u32 ee0[4] = {e0.x, e0.y, e0.z, e0.w};
      const u32 ee1[4] = {e1.x, e1.y, e1.z, e1.w};
      u32 w00[4], w01[4], w10[4], w11[4];
      #pragma unroll
      for (int i = 0; i < 4; ++i) {
        float c0v = bflo(ee0[i]), s0v = bfhi(ee0[i]);
        float c1v = bflo(ee1[i]), s1v = bfhi(ee1[i]);
        w00[i] = pack2(uu0[i] * c0v, -(uu0[i] * s0v));
        w01[i] = pack2(uu1[i] * c0v, -(uu1[i] * s0v));
        w10[i] = pack2(uu0[i] * c1v, -(uu0[i] * s1v));
        w11[i] = pack2(uu1[i] * c1v, -(uu1[i] * s1v));
      }
      bf16x8 fb = as_frag(bb);
      acc00 = __builtin_amdgcn_mfma_f32_16x16x32_bf16(
                  as_frag(make_uint4(w00[0], w00[1], w00[2], w00[3])), fb, acc00, 0, 0, 0);
      acc01 = __builtin_amdgcn_mfma_f32_16x16x32_bf16(
                  as_frag(make_uint4(w01[0], w01[1], w01[2], w01[3])), fb, acc01, 0, 0, 0);
      acc10 = __builtin_amdgcn_mfma_f32_16x16x32_bf16(
                  as_frag(make_uint4(w10[0], w10[1], w10[2], w10[3])), fb, acc10, 0, 0, 0);
      acc11 = __builtin_amdgcn_mfma_f32_16x16x32_bf16(
                  as_frag(make_uint4(w11[0], w11[1], w11[2], w11[3])), fb, acc11, 0, 0, 0);
    }
  }

  size_t base0 = (((size_t)s * 8 + b) * 16 + y0) * 2048;   // P[s][b][y][c][j]
  size_t base1 = (((size_t)s * 8 + b) * 16 + y1) * 2048;
  #pragma unroll
  for (int r = 0; r < 4; ++r) {
    int cr0 = kq * 4 + r, cr1 = cr0 + 16;
    P[base0 + cr0 * 64 + brow] = acc00[r];
    P[base0 + cr1 * 64 + brow] = acc01[r];
    P[base1 + cr0 * 64 + brow] = acc10[r];
    P[base1 + cr1 * 64 + brow] = acc11[r];
  }
}

// ---------------------------------------------------------------------------
// Phase 2 == r7 apply, with the emb matvec parallelized over all 512 threads
// (was 32 lanes x 128 serial iters).
__device__ __forceinline__ void phase2(int bid, int tid,
    const float* __restrict__ t, const float* __restrict__ w_freq,
    const float* __restrict__ b_freq, const float* __restrict__ w1,
    const float* __restrict__ w2, const float* __restrict__ P,
    u32* __restrict__ A32) {
  const int b = bid & 7, x = bid >> 3;
  const int m1 = x & 15, sel = x >> 4;

  __shared__ float uf_s[32][16][2];
  __shared__ float emb_s[16][2];
  __shared__ float part[512];

  for (int e = tid; e < 1024; e += 512) {
    int i = e >> 5, r = e & 31, yy = r >> 1, comp = r & 1;
    size_t base = (((size_t)(b * 16 + yy)) * 32 + i) * 64 + 2 * x + comp;
    float sacc = 0.f;
    #pragma unroll
    for (int ss = 0; ss < 8; ++ss) sacc += P[base + (size_t)ss * 262144];
    uf_s[i][yy][comp] = sacc;
  }
  {
    int jjl = tid & 31, kc = tid >> 5;           // kc 0..15
    int yy = jjl >> 1, pp = jjl & 1;
    int jj = ((m1 * 16 + yy) * 2 + sel) * 2 + pp;
    float sv = 0.f;
    #pragma unroll
    for (int k2 = 0; k2 < 8; ++k2) {
      int k = kc * 8 + k2;
      sv += t[b * TDIM + k] * w_freq[k * 1024 + jj];
    }
    part[tid] = sv;
  }
  __syncthreads();
  if (tid < 32) {
    int yy = tid >> 1, pp = tid & 1;
    int jj = ((m1 * 16 + yy) * 2 + sel) * 2 + pp;
    float acc = b_freq[jj];
    #pragma unroll
    for (int c2 = 0; c2 < 16; ++c2) acc += part[c2 * 32 + tid];
    emb_s[yy][pp] = acc;
  }
  __syncthreads();

  int o = tid >> 4, y = tid & 15;
  const float* wsel = sel ? w2 : w1;
  float fr = 0.f, fi = 0.f;
  #pragma unroll 4
  for (int i = 0; i < 32; ++i) {
    float2 w = *(const float2*)&wsel[(size_t)(((i * 32 + o) * 16 + m1) * 16 + y) * 2];
    float ur = uf_s[i][y][0], ui = uf_s[i][y][1];
    fr += ur * w.x - ui * w.y;
    fi += ur * w.y + ui * w.x;
  }
  float er = emb_s[y][0], ei = emb_s[y][1];
  float orr = fr * er - fi * ei;
  float oii = fr * ei + fi * er;
  A32[((b * 31 + y) * 32 + o) * 32 + x] = pack2(orr, oii);
  if (y > 0)
    A32[((b * 31 + (31 - y)) * 32 + o) * 32 + (31 - x)] = pack2(orr, -oii);
}

// ---------------------------------------------------------------------------
// Phase 3 == r7 inv (512 4-wave units on 256 8-wave blocks); E1out/E2out tables
// replaced by in-phase sincos (16/thread — trivial; deletes prep2 + 8MB ws).
__device__ __forceinline__ void phase3(int bid, int tid,
    const u32* __restrict__ A32, const float* __restrict__ x_out,
    float* __restrict__ Y) {
  const int b = bid & 7;
  const int un = tid >> 8;                     // unit 0/1
  const int nt = ((bid >> 3) << 1) | un;       // 0..63
  const int n0 = nt * 64;
  const int lt = tid & 255;
  const int lane = lt & 63, wu = lt >> 6;
  const int colw = lane & 15, kq = lane >> 4;

  __shared__ __align__(16) u16 Bgr[2][64 * 64];   // [n][k=2X+comp], swizzled
  __shared__ __align__(16) u16 Bgi[2][64 * 64];
  __shared__ u32 e2s[2][31 * 64];

  {
    const int n = lt & 63, Xg = lt >> 6;
    float x0 = x_out[(size_t)(b * NPTS + n0 + n) * 2];
    #pragma unroll
    for (int i = 0; i < 8; ++i) {
      int X = Xg * 8 + i;
      float k1x = (X < 16) ? (float)X : (float)(X - 32);
      float th = TWO_PI * x0 * k1x;
      float s1, c1; __sincosf(th, &s1, &c1);
      int byt = (4 * X) ^ ((n & 7) << 4);
      *(u32*)((char*)Bgr[un] + n * 128 + byt) = pack2(c1, -s1);
      *(u32*)((char*)Bgi[un] + n * 128 + byt) = pack2(s1, c1);
    }
  }
  {
    const int n = lt & 63;
    float x1 = x_out[(size_t)(b * NPTS + n0 + n) * 2 + 1];
    for (int idx = lt; idx < 1984; idx += 256) {
      int y = idx >> 6;
      float k2y = (y < 16) ? (float)y : (float)(y - 31);
      float th = TWO_PI * x1 * k2y;
      float s2, c2; __sincosf(th, &s2, &c2);
      e2s[un][idx] = pack2(c2, s2);
    }
  }
  __syncthreads();

  const int brow = wu * 16 + colw;
  bf16x8 bgr[2], bgi[2];
  #pragma unroll
  for (int ks = 0; ks < 2; ++ks) {
    int kb = ks * 64 + kq * 16;
    bgr[ks] = *(bf16x8*)((char*)Bgr[un] + brow * 128 + (kb ^ ((brow & 7) << 4)));
    bgi[ks] = *(bf16x8*)((char*)Bgi[un] + brow * 128 + (kb ^ ((brow & 7) << 4)));
  }

  f32x4 Y0 = {0,0,0,0}, Y1 = {0,0,0,0};
  const u32* Abase = A32 + (size_t)b * 31 * 1024;

  #pragma unroll 1
  for (int y = 0; y < 31; ++y) {
    const u32* p = Abase + y * 1024;
    bf16x8 af0 = *(bf16x8*)(p + colw * 32 + kq * 4);
    bf16x8 af1 = *(bf16x8*)(p + colw * 32 + 16 + kq * 4);
    bf16x8 af2 = *(bf16x8*)(p + (colw + 16) * 32 + kq * 4);
    bf16x8 af3 = *(bf16x8*)(p + (colw + 16) * 32 + 16 + kq * 4);
    f32x4 z = {0,0,0,0};
    f32x4 gr0 = __builtin_amdgcn_mfma_f32_16x16x32_bf16(af0, bgr[0], z, 0, 0, 0);
    gr0 = __builtin_amdgcn_mfma_f32_16x16x32_bf16(af1, bgr[1], gr0, 0, 0, 0);
    f32x4 gr1 = __builtin_amdgcn_mfma_f32_16x16x32_bf16(af2, bgr[0], z, 0, 0, 0);
    gr1 = __builtin_amdgcn_mfma_f32_16x16x32_bf16(af3, bgr[1], gr1, 0, 0, 0);
    f32x4 gi0 = __builtin_amdgcn_mfma_f32_16x16x32_bf16(af0, bgi[0], z, 0, 0, 0);
    gi0 = __builtin_amdgcn_mfma_f32_16x16x32_bf16(af1, bgi[1], gi0, 0, 0, 0);
    f32x4 gi1 = __builtin_amdgcn_mfma_f32_16x16x32_bf16(af2, bgi[0], z, 0, 0, 0);
    gi1 = __builtin_amdgcn_mfma_f32_16x16x32_bf16(af3, bgi[1], gi1, 0, 0, 0);
    u32 e2 = e2s[un][y * 64 + brow];
    float c2 = bflo(e2), s2 = bfhi(e2);
    #pragma unroll
    for (int r = 0; r < 4; ++r) {
      Y0[r] += gr0[r] * c2 - gi0[r] * s2;
      Y1[r] += gr1[r] * c2 - gi1[r] * s2;
    }
  }

  int n = n0 + brow;
  #pragma unroll
  for (int r = 0; r < 4; ++r) {
    Y[(size_t)(b * 32 + kq * 4 + r) * NPTS + n] = Y0[r];
    Y[(size_t)(b * 32 + kq * 4 + r + 16) * NPTS + n] = Y1[r];
  }
}

// ---------------------------------------------------------------------------
__global__ __launch_bounds__(512, 2) void fused_kernel(
    const float* __restrict__ u, const float* __restrict__ x_in,
    const float* __restrict__ x_out, const float* __restrict__ t,
    const float* __restrict__ w_freq, const float* __restrict__ b_freq,
    const float* __restrict__ w1, const float* __restrict__ w2,
    u32* E2in, u32* B_pre, float* P, u32* A32, float* Y) {
  cg::grid_group g = cg::this_grid();
  const int bid = blockIdx.x, tid = threadIdx.x;
  phase0(bid, tid, x_in, E2in, B_pre);
  __threadfence(); g.sync();
  phase1(bid, tid, u, E2in, B_pre, P);
  __threadfence(); g.sync();
  phase2(bid, tid, t, w_freq, b_freq, w1, w2, P, A32);
  __threadfence(); g.sync();
  phase3(bid, tid, A32, x_out, Y);
}

// Fallback path (plain kernels, same bodies) if cooperative launch fails.
__global__ __launch_bounds__(512) void p0_k(const float* x_in, u32* E2in, u32* B_pre) {
  phase0(blockIdx.x, threadIdx.x, x_in, E2in, B_pre);
}
__global__ __launch_bounds__(512) void p1_k(const float* u, const u32* E2in,
                                            const u32* B_pre, float* P) {
  phase1(blockIdx.x, threadIdx.x, u, E2in, B_pre, P);
}
__global__ __launch_bounds__(512) void p2_k(const float* t, const float* w_freq,
    const float* b_freq, const float* w1, const float* w2, const float* P, u32* A32) {
  phase2(blockIdx.x, threadIdx.x, t, w_freq, b_freq, w1, w2, P, A32);
}
__global__ __launch_bounds__(512) void p3_k(const u32* A32, const float* x_out, float* Y) {
  phase3(blockIdx.x, threadIdx.x, A32, x_out, Y);
}

// ---------------------------------------------------------------------------
extern "C" void kernel_launch(void* const* d_in, const int* in_sizes, int n_in,
                              void* d_out, int out_size, void* d_ws, size_t ws_size,
                              hipStream_t stream) {
  const float* u      = (const float*)d_in[0];
  const float* x_in   = (const float*)d_in[1];
  const float* x_out  = (const float*)d_in[2];
  const float* t      = (const float*)d_in[3];
  const float* w_freq = (const float*)d_in[4];
  const float* b_freq = (const float*)d_in[5];
  const float* w1     = (const float*)d_in[6];
  const float* w2     = (const float*)d_in[7];
  float* Y = (float*)d_out;

  u32* E2in  = (u32*)d_ws;                 // 524288
  u32* B_pre = E2in + 524288;              // 2097152
  float* P   = (float*)(B_pre + 2097152);  // 2097152 f32
  u32* A32   = E2in;                       // alias: E2in dead after phase1

  void* kargs[] = {(void*)&u, (void*)&x_in, (void*)&x_out, (void*)&t,
                   (void*)&w_freq, (void*)&b_freq, (void*)&w1, (void*)&w2,
                   (void*)&E2in, (void*)&B_pre, (void*)&P, (void*)&A32, (void*)&Y};
  hipError_t err = hipLaunchCooperativeKernel((const void*)fused_kernel,
                                              dim3(256), dim3(512), kargs, 0, stream);
  if (err != hipSuccess) {
    p0_k<<<256, 512, 0, stream>>>(x_in, E2in, B_pre);
    p1_k<<<256, 512, 0, stream>>>(u, E2in, B_pre, P);
    p2_k<<<256, 512, 0, stream>>>(t, w_freq, b_freq, w1, w2, P, A32);
    p3_k<<<256, 512, 0, stream>>>(A32, x_out, Y);
  }
}

// Round 9
// 96.834 us; speedup vs baseline: 3.8563x; 3.8563x over previous
//
#include <hip/hip_runtime.h>
#include <hip/hip_bf16.h>

// SpectralConv2d: B=8, CIN=COUT=32, N=4096, modes 32x x 31y (u_ft needs y 0..15)
// r9 = r7 split kernels + occupancy fix (latency-bound per r8 counters:
// whole pipeline moves only ~60MB; nothing is BW-bound — the limit is exposed
// L2 latency at 2 waves/SIMD). Both GEMMs split the c-dim -> grid 1024,
// 4 waves/SIMD. prep2 merged into inv (in-kernel sincos, r8-verified math);
// apply emb matvec parallelized (r8-verified math). 4 kernels total.
//
// ws (u32 slots), 18.0 MB:
//   E2in  [8][16][4096]           : 524288   (aliased by A32 after uft)
//   B_pre [8][64nt][64j][64n]     : 2097152
//   P     [8s][8b][16y][32c][64j] : 2097152 f32

#define NPTS 4096
#define TDIM 128
#define TWO_PI 6.283185307179586f

typedef __attribute__((ext_vector_type(8))) short bf16x8;
typedef __attribute__((ext_vector_type(4))) float f32x4;
typedef unsigned int u32;
typedef unsigned short u16;

__device__ __forceinline__ u32 pack2(float a, float b) {
  __hip_bfloat162 h = __float22bfloat162_rn(make_float2(a, b));  // v_cvt_pk_bf16_f32
  u32 r; __builtin_memcpy(&r, &h, 4); return r;
}
__device__ __forceinline__ float bflo(u32 u) { return __uint_as_float(u << 16); }
__device__ __forceinline__ float bfhi(u32 u) { return __uint_as_float(u & 0xFFFF0000u); }
__device__ __forceinline__ bf16x8 as_frag(uint4 v) {
  bf16x8 f; __builtin_memcpy(&f, &v, 16); return f;
}

// ---------------------------------------------------------------------------
// prep1 (unchanged r7): E2in (y 0..15) + B_pre (conj(E1in)), linear layout.
__global__ __launch_bounds__(256) void prep1_kernel(
    const float* __restrict__ x_in, u32* __restrict__ E2in, u32* __restrict__ B_pre) {
  const int bid = blockIdx.x;              // 512
  const int b = bid & 7, ntile = bid >> 3; // 0..63
  const int tid = threadIdx.x;
  const int nl = tid & 63, task = tid >> 6;
  const int n = ntile * 64 + nl;
  float2 xv = *(const float2*)&x_in[(size_t)(b * NPTS + n) * 2];
  if (task < 2) {
    #pragma unroll
    for (int k = 0; k < 8; ++k) {
      int y = task * 8 + k;                          // 0..15 -> k2y = y
      float th = TWO_PI * xv.y * (float)y;
      float s, c; __sincosf(th, &s, &c);
      E2in[((b * 16 + y) << 12) + n] = pack2(c, s);
    }
  } else {
    u32* base = B_pre + (size_t)(b * 64 + ntile) * 4096;
    #pragma unroll
    for (int k = 0; k < 16; ++k) {
      int x = (task - 2) * 16 + k;
      float k1x = (x < 16) ? (float)x : (float)(x - 32);
      float th = TWO_PI * xv.x * k1x;
      float s, c; __sincosf(th, &s, &c);
      base[(2 * x) * 64 + nl]     = pack2(c, s);     // conj(e1) re-row
      base[(2 * x + 1) * 64 + nl] = pack2(-s, c);    // conj(e1) im-row
    }
  }
}

// ---------------------------------------------------------------------------
// uft: grid 1024 = (b, yp, s, chalf). Each block: ONE c-half (16 rows), both
// y's. No LDS/barriers; A-frags in regs; B-frags from L2-hot B_pre.
__global__ __launch_bounds__(256, 4) void uft_kernel(
    const float* __restrict__ u, const u32* __restrict__ E2in,
    const u32* __restrict__ B_pre, float* __restrict__ P) {
  const int bid = blockIdx.x;
  const int b = bid & 7;                   // XCD pin
  const int rest = bid >> 3;               // 0..127
  const int yp = rest & 7;
  const int s = (rest >> 3) & 7;
  const int chalf = rest >> 6;             // 0/1
  const int tid = threadIdx.x;
  const int lane = tid & 63, wv = tid >> 6;

  const int y0 = 2 * yp, y1 = 2 * yp + 1;
  const int colw = lane & 15, kq = lane >> 4;
  const int brow = wv * 16 + colw;
  const int c = colw + 16 * chalf;

  const float* up = &u[(size_t)(b * 32 + c) * NPTS];
  const u32* e0p = &E2in[(b * 16 + y0) << 12];
  const u32* e1p = &E2in[(b * 16 + y1) << 12];
  const u32* bp  = B_pre + (size_t)(b * 64 + s * 8) * 4096 + brow * 64 + kq * 4;

  f32x4 acc0 = {0,0,0,0}, acc1 = {0,0,0,0};

  #pragma unroll 1
  for (int ch = 0; ch < 8; ++ch) {
    const int nq0 = s * 512 + ch * 64 + kq * 4;
    #pragma unroll
    for (int ks = 0; ks < 4; ++ks) {
      const int nq = nq0 + ks * 16;
      float4 uv = *(const float4*)(up + nq);
      uint4 e0 = *(const uint4*)(e0p + nq);
      uint4 e1 = *(const uint4*)(e1p + nq);
      uint4 bb = *(const uint4*)(bp + (size_t)ch * 4096 + ks * 16);

      const float uu[4] = {uv.x, uv.y, uv.z, uv.w};
      const u32 ee0[4] = {e0.x, e0.y, e0.z, e0.w};
      const u32 ee1[4] = {e1.x, e1.y, e1.z, e1.w};
      u32 w0[4], w1[4];
      #pragma unroll
      for (int i = 0; i < 4; ++i) {
        float c0v = bflo(ee0[i]), s0v = bfhi(ee0[i]);
        float c1v = bflo(ee1[i]), s1v = bfhi(ee1[i]);
        w0[i] = pack2(uu[i] * c0v, -(uu[i] * s0v));   // A(c, y0)
        w1[i] = pack2(uu[i] * c1v, -(uu[i] * s1v));   // A(c, y1)
      }
      bf16x8 fb = as_frag(bb);
      acc0 = __builtin_amdgcn_mfma_f32_16x16x32_bf16(
                 as_frag(make_uint4(w0[0], w0[1], w0[2], w0[3])), fb, acc0, 0, 0, 0);
      acc1 = __builtin_amdgcn_mfma_f32_16x16x32_bf16(
                 as_frag(make_uint4(w1[0], w1[1], w1[2], w1[3])), fb, acc1, 0, 0, 0);
    }
  }

  size_t base0 = (((size_t)s * 8 + b) * 16 + y0) * 2048;   // P[s][b][y][c][j]
  size_t base1 = (((size_t)s * 8 + b) * 16 + y1) * 2048;
  #pragma unroll
  for (int r = 0; r < 4; ++r) {
    int cr = kq * 4 + r + 16 * chalf;
    P[base0 + cr * 64 + brow] = acc0[r];
    P[base1 + cr * 64 + brow] = acc1[r];
  }
}

// ---------------------------------------------------------------------------
// apply (r7 shape + r8's parallel emb matvec): 8-way split-K reduce + emb +
// Hermitian ext; writes bf16-packed A32[b][y0..30][c][j=2X+comp].
__global__ __launch_bounds__(512) void apply_kernel(
    const float* __restrict__ t, const float* __restrict__ w_freq,
    const float* __restrict__ b_freq, const float* __restrict__ w1,
    const float* __restrict__ w2, const float* __restrict__ P,
    u32* __restrict__ A32) {
  const int x = blockIdx.x, b = blockIdx.y;
  const int tid = threadIdx.x;
  const int m1 = x & 15, sel = x >> 4;

  __shared__ float uf_s[32][16][2];
  __shared__ float emb_s[16][2];
  __shared__ float part[512];

  for (int e = tid; e < 1024; e += 512) {
    int i = e >> 5, r = e & 31, yy = r >> 1, comp = r & 1;
    size_t base = (((size_t)(b * 16 + yy)) * 32 + i) * 64 + 2 * x + comp;
    float sacc = 0.f;
    #pragma unroll
    for (int ss = 0; ss < 8; ++ss) sacc += P[base + (size_t)ss * 262144];
    uf_s[i][yy][comp] = sacc;
  }
  {
    int jjl = tid & 31, kc = tid >> 5;           // kc 0..15
    int yy = jjl >> 1, pp = jjl & 1;
    int jj = ((m1 * 16 + yy) * 2 + sel) * 2 + pp;
    float sv = 0.f;
    #pragma unroll
    for (int k2 = 0; k2 < 8; ++k2) {
      int k = kc * 8 + k2;
      sv += t[b * TDIM + k] * w_freq[k * 1024 + jj];
    }
    part[tid] = sv;
  }
  __syncthreads();
  if (tid < 32) {
    int yy = tid >> 1, pp = tid & 1;
    int jj = ((m1 * 16 + yy) * 2 + sel) * 2 + pp;
    float acc = b_freq[jj];
    #pragma unroll
    for (int c2 = 0; c2 < 16; ++c2) acc += part[c2 * 32 + tid];
    emb_s[yy][pp] = acc;
  }
  __syncthreads();

  int o = tid >> 4, y = tid & 15;
  const float* wsel = sel ? w2 : w1;
  float fr = 0.f, fi = 0.f;
  #pragma unroll 4
  for (int i = 0; i < 32; ++i) {
    float2 w = *(const float2*)&wsel[(size_t)(((i * 32 + o) * 16 + m1) * 16 + y) * 2];
    float ur = uf_s[i][y][0], ui = uf_s[i][y][1];
    fr += ur * w.x - ui * w.y;
    fi += ur * w.y + ui * w.x;
  }
  float er = emb_s[y][0], ei = emb_s[y][1];
  float orr = fr * er - fi * ei;
  float oii = fr * ei + fi * er;
  A32[((b * 31 + y) * 32 + o) * 32 + x] = pack2(orr, oii);
  if (y > 0)
    A32[((b * 31 + (31 - y)) * 32 + o) * 32 + (31 - x)] = pack2(orr, -oii);
}

// ---------------------------------------------------------------------------
// inv: grid 1024 = (b, nt, chalf). Cis values computed in-kernel (prep2
// deleted; r8-verified). Each block: one c-half, one 64-n tile.
__global__ __launch_bounds__(256, 4) void inv_kernel(
    const u32* __restrict__ A32, const float* __restrict__ x_out,
    float* __restrict__ Y) {
  const int bid = blockIdx.x;
  const int b = bid & 7;
  const int rest = bid >> 3;               // 0..127
  const int nt = rest & 63;
  const int h = rest >> 6;                 // c-half 0/1
  const int n0 = nt * 64;
  const int tid = threadIdx.x;
  const int lane = tid & 63, wv = tid >> 6;
  const int colw = lane & 15, kq = lane >> 4;

  __shared__ __align__(16) u16 Bgr[64 * 64];   // [n][k=2X+comp], swizzled
  __shared__ __align__(16) u16 Bgi[64 * 64];
  __shared__ u32 e2s[31 * 64];

  {
    const int n = tid & 63, Xg = tid >> 6;
    float x0 = x_out[(size_t)(b * NPTS + n0 + n) * 2];
    #pragma unroll
    for (int i = 0; i < 8; ++i) {
      int X = Xg * 8 + i;
      float k1x = (X < 16) ? (float)X : (float)(X - 32);
      float th = TWO_PI * x0 * k1x;
      float s1, c1; __sincosf(th, &s1, &c1);
      int byt = (4 * X) ^ ((n & 7) << 4);
      *(u32*)((char*)Bgr + n * 128 + byt) = pack2(c1, -s1);
      *(u32*)((char*)Bgi + n * 128 + byt) = pack2(s1, c1);
    }
  }
  {
    const int n = tid & 63;
    float x1 = x_out[(size_t)(b * NPTS + n0 + n) * 2 + 1];
    for (int idx = tid; idx < 1984; idx += 256) {
      int y = idx >> 6;
      float k2y = (y < 16) ? (float)y : (float)(y - 31);
      float th = TWO_PI * x1 * k2y;
      float s2, c2; __sincosf(th, &s2, &c2);
      e2s[idx] = pack2(c2, s2);
    }
  }
  __syncthreads();

  const int brow = wv * 16 + colw;
  bf16x8 bgr[2], bgi[2];
  #pragma unroll
  for (int ks = 0; ks < 2; ++ks) {
    int kb = ks * 64 + kq * 16;
    bgr[ks] = *(bf16x8*)((char*)Bgr + brow * 128 + (kb ^ ((brow & 7) << 4)));
    bgi[ks] = *(bf16x8*)((char*)Bgi + brow * 128 + (kb ^ ((brow & 7) << 4)));
  }

  f32x4 Yh = {0,0,0,0};
  const u32* Abase = A32 + (size_t)b * 31 * 1024;
  const int crow = colw + 16 * h;

  #pragma unroll 1
  for (int y = 0; y < 31; ++y) {
    const u32* p = Abase + y * 1024;
    bf16x8 af0 = *(bf16x8*)(p + crow * 32 + kq * 4);
    bf16x8 af1 = *(bf16x8*)(p + crow * 32 + 16 + kq * 4);
    f32x4 z = {0,0,0,0};
    f32x4 gr = __builtin_amdgcn_mfma_f32_16x16x32_bf16(af0, bgr[0], z, 0, 0, 0);
    gr = __builtin_amdgcn_mfma_f32_16x16x32_bf16(af1, bgr[1], gr, 0, 0, 0);
    f32x4 gi = __builtin_amdgcn_mfma_f32_16x16x32_bf16(af0, bgi[0], z, 0, 0, 0);
    gi = __builtin_amdgcn_mfma_f32_16x16x32_bf16(af1, bgi[1], gi, 0, 0, 0);
    u32 e2 = e2s[y * 64 + brow];
    float c2 = bflo(e2), s2 = bfhi(e2);
    #pragma unroll
    for (int r = 0; r < 4; ++r) Yh[r] += gr[r] * c2 - gi[r] * s2;
  }

  int n = n0 + brow;
  #pragma unroll
  for (int r = 0; r < 4; ++r)
    Y[(size_t)(b * 32 + kq * 4 + r + 16 * h) * NPTS + n] = Yh[r];
}

// ---------------------------------------------------------------------------
extern "C" void kernel_launch(void* const* d_in, const int* in_sizes, int n_in,
                              void* d_out, int out_size, void* d_ws, size_t ws_size,
                              hipStream_t stream) {
  const float* u      = (const float*)d_in[0];
  const float* x_in   = (const float*)d_in[1];
  const float* x_out  = (const float*)d_in[2];
  const float* t      = (const float*)d_in[3];
  const float* w_freq = (const float*)d_in[4];
  const float* b_freq = (const float*)d_in[5];
  const float* w1     = (const float*)d_in[6];
  const float* w2     = (const float*)d_in[7];
  float* Y = (float*)d_out;

  u32* E2in  = (u32*)d_ws;                 // 524288
  u32* B_pre = E2in + 524288;              // 2097152
  float* P   = (float*)(B_pre + 2097152);  // 2097152 f32
  u32* A32   = E2in;                       // alias: E2in dead after uft

  prep1_kernel<<<512, 256, 0, stream>>>(x_in, E2in, B_pre);
  uft_kernel<<<1024, 256, 0, stream>>>(u, E2in, B_pre, P);
  apply_kernel<<<dim3(32, 8), 512, 0, stream>>>(t, w_freq, b_freq, w1, w2, P, A32);
  inv_kernel<<<1024, 256, 0, stream>>>(A32, x_out, Y);
}

// Round 10
// 82.458 us; speedup vs baseline: 4.5286x; 1.1743x over previous
//
#include <hip/hip_runtime.h>
#include <hip/hip_bf16.h>

// SpectralConv2d: B=8, CIN=COUT=32, N=4096, modes 32x x 31y (u_ft needs y 0..15)
// r10: both GEMMs LDS-staged with coalesced cooperative loads + swizzled
// ds_read_b128 frags (r9 showed direct-from-global frags = 16-way scattered
// loads at VGPR=24 -> latency-serialized, 43us). Math identical to r9 (passed).
//
// ws (u32 slots), 18.0 MB:
//   E2in  [8][16][4096]           : 524288   (aliased by A32 after uft)
//   B_pre [8][64nt][64j][64n]     : 2097152
//   P     [8s][8b][16y][32c][64j] : 2097152 f32

#define NPTS 4096
#define TDIM 128
#define TWO_PI 6.283185307179586f

typedef __attribute__((ext_vector_type(8))) short bf16x8;
typedef __attribute__((ext_vector_type(4))) float f32x4;
typedef unsigned int u32;
typedef unsigned short u16;

__device__ __forceinline__ u32 pack2(float a, float b) {
  __hip_bfloat162 h = __float22bfloat162_rn(make_float2(a, b));  // v_cvt_pk_bf16_f32
  u32 r; __builtin_memcpy(&r, &h, 4); return r;
}
__device__ __forceinline__ float bflo(u32 u) { return __uint_as_float(u << 16); }
__device__ __forceinline__ float bfhi(u32 u) { return __uint_as_float(u & 0xFFFF0000u); }

// ---------------------------------------------------------------------------
// prep1 (r9 verbatim): E2in (y 0..15) + B_pre (conj(E1in)), linear layout.
__global__ __launch_bounds__(256) void prep1_kernel(
    const float* __restrict__ x_in, u32* __restrict__ E2in, u32* __restrict__ B_pre) {
  const int bid = blockIdx.x;              // 512
  const int b = bid & 7, ntile = bid >> 3; // 0..63
  const int tid = threadIdx.x;
  const int nl = tid & 63, task = tid >> 6;
  const int n = ntile * 64 + nl;
  float2 xv = *(const float2*)&x_in[(size_t)(b * NPTS + n) * 2];
  if (task < 2) {
    #pragma unroll
    for (int k = 0; k < 8; ++k) {
      int y = task * 8 + k;                          // 0..15 -> k2y = y
      float th = TWO_PI * xv.y * (float)y;
      float s, c; __sincosf(th, &s, &c);
      E2in[((b * 16 + y) << 12) + n] = pack2(c, s);
    }
  } else {
    u32* base = B_pre + (size_t)(b * 64 + ntile) * 4096;
    #pragma unroll
    for (int k = 0; k < 16; ++k) {
      int x = (task - 2) * 16 + k;
      float k1x = (x < 16) ? (float)x : (float)(x - 32);
      float th = TWO_PI * xv.x * k1x;
      float s, c; __sincosf(th, &s, &c);
      base[(2 * x) * 64 + nl]     = pack2(c, s);     // conj(e1) re-row
      base[(2 * x + 1) * 64 + nl] = pack2(-s, c);    // conj(e1) im-row
    }
  }
}

// ---------------------------------------------------------------------------
// uft: grid 256 = (b8, s8, yq4). Per block: 4 y's, all 32 c, 512-n range in
// 8 chunks of 64 n (K=128). A built in regs (coalesced u/E2 loads) ->
// XOR-swizzled LDS; B_pre chunk staged coalesced -> swizzled LDS.
// Wave w = j-tile w. B-frag reused across 4y x 2m.
__global__ __launch_bounds__(256) void uft_kernel(
    const float* __restrict__ u, const u32* __restrict__ E2in,
    const u32* __restrict__ B_pre, float* __restrict__ P) {
  const int bid = blockIdx.x;
  const int b = bid & 7;                   // XCD pin
  const int rest = bid >> 3;               // 0..31
  const int s = rest & 7;
  const int yq = rest >> 3;                // 0..3
  const int tid = threadIdx.x;
  const int lane = tid & 63, jt = tid >> 6;
  const int colw = lane & 15, kq = lane >> 4;

  __shared__ __align__(16) u16 As[4 * 32 * 128];   // 32 KB: rows (y*32+c), 256B
  __shared__ __align__(16) u16 Bs[64 * 128];       // 16 KB: rows j, 256B

  f32x4 acc[4][2];
  #pragma unroll
  for (int yl = 0; yl < 4; ++yl)
    #pragma unroll
    for (int m = 0; m < 2; ++m) acc[yl][m] = (f32x4){0.f, 0.f, 0.f, 0.f};

  for (int ch = 0; ch < 8; ++ch) {
    const int n0 = s * 512 + ch * 64;
    const int nt = s * 8 + ch;

    // issue all chunk loads (coalesced; overlap the barrier wait)
    float4 uv[8]; uint4 ev[8]; uint4 bv[4];
    #pragma unroll
    for (int i = 0; i < 8; ++i) {
      int idx = tid + i * 256;                       // 0..2047
      int y = idx >> 9, c = (idx >> 4) & 31, q = idx & 15;
      uv[i] = *(const float4*)&u[(size_t)(b * 32 + c) * NPTS + n0 + q * 4];
      ev[i] = *(const uint4*)&E2in[((b * 16 + yq * 4 + y) << 12) + n0 + q * 4];
    }
    #pragma unroll
    for (int i = 0; i < 4; ++i) {
      int idx = tid + i * 256;                       // 0..1023
      int j = idx >> 4, seg = idx & 15;
      bv[i] = *(const uint4*)&B_pre[(size_t)(b * 64 + nt) * 4096 + j * 64 + seg * 4];
    }
    __syncthreads();   // previous chunk's MFMA reads done

    // build A = u .* conj(E2_y) and stage (16B = 4 complex n)
    #pragma unroll
    for (int i = 0; i < 8; ++i) {
      int idx = tid + i * 256;
      int y = idx >> 9, c = (idx >> 4) & 31, q = idx & 15;
      const float uu[4] = {uv[i].x, uv[i].y, uv[i].z, uv[i].w};
      const u32 ee[4] = {ev[i].x, ev[i].y, ev[i].z, ev[i].w};
      uint4 w;
      u32* wp = &w.x;
      #pragma unroll
      for (int p2 = 0; p2 < 4; ++p2)
        wp[p2] = pack2(uu[p2] * bflo(ee[p2]), -(uu[p2] * bfhi(ee[p2])));
      *(uint4*)((char*)As + (y * 32 + c) * 256 + ((q * 16) ^ ((c & 7) << 4))) = w;
    }
    // stage B chunk (swizzled)
    #pragma unroll
    for (int i = 0; i < 4; ++i) {
      int idx = tid + i * 256;
      int j = idx >> 4, seg = idx & 15;
      *(uint4*)((char*)Bs + j * 256 + ((seg * 16) ^ ((j & 7) << 4))) = bv[i];
    }
    __syncthreads();

    // MFMA: 4 k-steps; B-frag reused across 4y x 2m
    const int swz = (colw & 7) << 4;
    #pragma unroll
    for (int ks = 0; ks < 4; ++ks) {
      const int kb = ks * 64 + kq * 16;
      bf16x8 fb = *(bf16x8*)((char*)Bs + (jt * 16 + colw) * 256 + (kb ^ swz));
      #pragma unroll
      for (int yl = 0; yl < 4; ++yl) {
        bf16x8 a0 = *(bf16x8*)((char*)As + (yl * 32 + colw) * 256 + (kb ^ swz));
        bf16x8 a1 = *(bf16x8*)((char*)As + (yl * 32 + 16 + colw) * 256 + (kb ^ swz));
        acc[yl][0] = __builtin_amdgcn_mfma_f32_16x16x32_bf16(a0, fb, acc[yl][0], 0, 0, 0);
        acc[yl][1] = __builtin_amdgcn_mfma_f32_16x16x32_bf16(a1, fb, acc[yl][1], 0, 0, 0);
      }
    }
  }

  // epilogue: P[s][b][y][c][j]; D row = kq*4+r (c within m-tile), col = colw (j)
  #pragma unroll
  for (int yl = 0; yl < 4; ++yl) {
    size_t base = (((size_t)s * 8 + b) * 16 + yq * 4 + yl) * 2048;
    #pragma unroll
    for (int m = 0; m < 2; ++m)
      #pragma unroll
      for (int r = 0; r < 4; ++r)
        P[base + (m * 16 + kq * 4 + r) * 64 + jt * 16 + colw] = acc[yl][m][r];
  }
}

// ---------------------------------------------------------------------------
// apply (r9 verbatim): 8-way split-K reduce + emb + Hermitian ext; writes
// bf16-packed A32[b][y0..30][c][j=2X+comp].
__global__ __launch_bounds__(512) void apply_kernel(
    const float* __restrict__ t, const float* __restrict__ w_freq,
    const float* __restrict__ b_freq, const float* __restrict__ w1,
    const float* __restrict__ w2, const float* __restrict__ P,
    u32* __restrict__ A32) {
  const int x = blockIdx.x, b = blockIdx.y;
  const int tid = threadIdx.x;
  const int m1 = x & 15, sel = x >> 4;

  __shared__ float uf_s[32][16][2];
  __shared__ float emb_s[16][2];
  __shared__ float part[512];

  for (int e = tid; e < 1024; e += 512) {
    int i = e >> 5, r = e & 31, yy = r >> 1, comp = r & 1;
    size_t base = (((size_t)(b * 16 + yy)) * 32 + i) * 64 + 2 * x + comp;
    float sacc = 0.f;
    #pragma unroll
    for (int ss = 0; ss < 8; ++ss) sacc += P[base + (size_t)ss * 262144];
    uf_s[i][yy][comp] = sacc;
  }
  {
    int jjl = tid & 31, kc = tid >> 5;           // kc 0..15
    int yy = jjl >> 1, pp = jjl & 1;
    int jj = ((m1 * 16 + yy) * 2 + sel) * 2 + pp;
    float sv = 0.f;
    #pragma unroll
    for (int k2 = 0; k2 < 8; ++k2) {
      int k = kc * 8 + k2;
      sv += t[b * TDIM + k] * w_freq[k * 1024 + jj];
    }
    part[tid] = sv;
  }
  __syncthreads();
  if (tid < 32) {
    int yy = tid >> 1, pp = tid & 1;
    int jj = ((m1 * 16 + yy) * 2 + sel) * 2 + pp;
    float acc = b_freq[jj];
    #pragma unroll
    for (int c2 = 0; c2 < 16; ++c2) acc += part[c2 * 32 + tid];
    emb_s[yy][pp] = acc;
  }
  __syncthreads();

  int o = tid >> 4, y = tid & 15;
  const float* wsel = sel ? w2 : w1;
  float fr = 0.f, fi = 0.f;
  #pragma unroll 4
  for (int i = 0; i < 32; ++i) {
    float2 w = *(const float2*)&wsel[(size_t)(((i * 32 + o) * 16 + m1) * 16 + y) * 2];
    float ur = uf_s[i][y][0], ui = uf_s[i][y][1];
    fr += ur * w.x - ui * w.y;
    fi += ur * w.y + ui * w.x;
  }
  float er = emb_s[y][0], ei = emb_s[y][1];
  float orr = fr * er - fi * ei;
  float oii = fr * ei + fi * er;
  A32[((b * 31 + y) * 32 + o) * 32 + x] = pack2(orr, oii);
  if (y > 0)
    A32[((b * 31 + (31 - y)) * 32 + o) * 32 + (31 - x)] = pack2(orr, -oii);
}

// ---------------------------------------------------------------------------
// inv: grid 1024 = (b, nt64, h2). Bg/e2s prologue (r9 verbatim math); per-y
// A-slice (2 KB) staged cooperatively to LDS w/ 1-iter reg prefetch; frags via
// swizzled ds_read_b128. 4 blocks/CU -> barrier stalls overlap across blocks.
__global__ __launch_bounds__(256) void inv_kernel(
    const u32* __restrict__ A32, const float* __restrict__ x_out,
    float* __restrict__ Y) {
  const int bid = blockIdx.x;
  const int b = bid & 7;
  const int rest = bid >> 3;               // 0..127
  const int nt = rest & 63;
  const int h = rest >> 6;                 // c-half 0/1
  const int n0 = nt * 64;
  const int tid = threadIdx.x;
  const int lane = tid & 63, wv = tid >> 6;
  const int colw = lane & 15, kq = lane >> 4;

  __shared__ __align__(16) u16 Bgr[64 * 64];   // [n][k=2X+comp], swizzled
  __shared__ __align__(16) u16 Bgi[64 * 64];
  __shared__ u32 e2s[31 * 64];
  __shared__ __align__(16) u16 Asl[16 * 64];   // 2 KB: rows cl (c-half), 128B

  {
    const int n = tid & 63, Xg = tid >> 6;
    float x0 = x_out[(size_t)(b * NPTS + n0 + n) * 2];
    #pragma unroll
    for (int i = 0; i < 8; ++i) {
      int X = Xg * 8 + i;
      float k1x = (X < 16) ? (float)X : (float)(X - 32);
      float th = TWO_PI * x0 * k1x;
      float s1, c1; __sincosf(th, &s1, &c1);
      int byt = (4 * X) ^ ((n & 7) << 4);
      *(u32*)((char*)Bgr + n * 128 + byt) = pack2(c1, -s1);
      *(u32*)((char*)Bgi + n * 128 + byt) = pack2(s1, c1);
    }
  }
  {
    const int n = tid & 63;
    float x1 = x_out[(size_t)(b * NPTS + n0 + n) * 2 + 1];
    for (int idx = tid; idx < 1984; idx += 256) {
      int y = idx >> 6;
      float k2y = (y < 16) ? (float)y : (float)(y - 31);
      float th = TWO_PI * x1 * k2y;
      float s2, c2; __sincosf(th, &s2, &c2);
      e2s[idx] = pack2(c2, s2);
    }
  }

  // A-stage: 128 threads x 16B cover the 2 KB slice
  const u32* Abase = A32 + (size_t)b * 31 * 1024 + h * 512;   // + y*1024 + cl*32
  const bool stager = tid < 128;
  const int cl = tid >> 3, seg = tid & 7;
  uint4 pA = {0u, 0u, 0u, 0u};
  if (stager) pA = *(const uint4*)(Abase + cl * 32 + seg * 4);   // y = 0
  __syncthreads();   // Bg/e2s ready

  const int brow = wv * 16 + colw;
  bf16x8 bgr[2], bgi[2];
  #pragma unroll
  for (int ks = 0; ks < 2; ++ks) {
    int kb = ks * 64 + kq * 16;
    bgr[ks] = *(bf16x8*)((char*)Bgr + brow * 128 + (kb ^ ((brow & 7) << 4)));
    bgi[ks] = *(bf16x8*)((char*)Bgi + brow * 128 + (kb ^ ((brow & 7) << 4)));
  }

  f32x4 Yh = {0.f, 0.f, 0.f, 0.f};
  const int swz = (colw & 7) << 4;

  #pragma unroll 1
  for (int y = 0; y < 31; ++y) {
    if (stager)
      *(uint4*)((char*)Asl + cl * 128 + ((seg * 16) ^ ((cl & 7) << 4))) = pA;
    __syncthreads();   // A_y staged
    if (y < 30 && stager)
      pA = *(const uint4*)(Abase + (y + 1) * 1024 + cl * 32 + seg * 4);  // prefetch

    bf16x8 af0 = *(bf16x8*)((char*)Asl + colw * 128 + ((kq * 16) ^ swz));
    bf16x8 af1 = *(bf16x8*)((char*)Asl + colw * 128 + ((64 + kq * 16) ^ swz));
    f32x4 z = {0.f, 0.f, 0.f, 0.f};
    f32x4 gr = __builtin_amdgcn_mfma_f32_16x16x32_bf16(af0, bgr[0], z, 0, 0, 0);
    gr = __builtin_amdgcn_mfma_f32_16x16x32_bf16(af1, bgr[1], gr, 0, 0, 0);
    f32x4 gi = __builtin_amdgcn_mfma_f32_16x16x32_bf16(af0, bgi[0], z, 0, 0, 0);
    gi = __builtin_amdgcn_mfma_f32_16x16x32_bf16(af1, bgi[1], gi, 0, 0, 0);
    u32 e2 = e2s[y * 64 + brow];
    float c2 = bflo(e2), s2 = bfhi(e2);
    #pragma unroll
    for (int r = 0; r < 4; ++r) Yh[r] += gr[r] * c2 - gi[r] * s2;
    __syncthreads();   // MFMA reads done before next overwrite
  }

  int n = n0 + brow;
  #pragma unroll
  for (int r = 0; r < 4; ++r)
    Y[(size_t)(b * 32 + kq * 4 + r + 16 * h) * NPTS + n] = Yh[r];
}

// ---------------------------------------------------------------------------
extern "C" void kernel_launch(void* const* d_in, const int* in_sizes, int n_in,
                              void* d_out, int out_size, void* d_ws, size_t ws_size,
                              hipStream_t stream) {
  const float* u      = (const float*)d_in[0];
  const float* x_in   = (const float*)d_in[1];
  const float* x_out  = (const float*)d_in[2];
  const float* t      = (const float*)d_in[3];
  const float* w_freq = (const float*)d_in[4];
  const float* b_freq = (const float*)d_in[5];
  const float* w1     = (const float*)d_in[6];
  const float* w2     = (const float*)d_in[7];
  float* Y = (float*)d_out;

  u32* E2in  = (u32*)d_ws;                 // 524288
  u32* B_pre = E2in + 524288;              // 2097152
  float* P   = (float*)(B_pre + 2097152);  // 2097152 f32
  u32* A32   = E2in;                       // alias: E2in dead after uft

  prep1_kernel<<<512, 256, 0, stream>>>(x_in, E2in, B_pre);
  uft_kernel<<<256, 256, 0, stream>>>(u, E2in, B_pre, P);
  apply_kernel<<<dim3(32, 8), 512, 0, stream>>>(t, w_freq, b_freq, w1, w2, P, A32);
  inv_kernel<<<1024, 256, 0, stream>>>(A32, x_out, Y);
}